// Round 4
// baseline (1197.832 us; speedup 1.0000x reference)
//
#include <hip/hip_runtime.h>

#define HIDF 128

static inline int cdiv(int a, int b) { return (a + b - 1) / b; }
static inline size_t alup(size_t b) { return (b + 255) & ~(size_t)255; }

// ---- degree count over dst ----
__global__ void k_deg(const int* __restrict__ dst, int E, int* __restrict__ deg) {
    int i = blockIdx.x * blockDim.x + threadIdx.x;
    if (i < E) atomicAdd(&deg[dst[i]], 1);
}

// ---- dinv = rsqrt(max(deg,1)) ----
__global__ void k_dinv(const int* __restrict__ deg, int N, float* __restrict__ dinv) {
    int i = blockIdx.x * blockDim.x + threadIdx.x;
    if (i < N) {
        float d = (float)deg[i];
        dinv[i] = rsqrtf(fmaxf(d, 1.0f));
    }
}

// ---- coefficients: cL[j]=gamma_L[j]; cH[j]=(-1)^j sum_{k>=j} gamma_H[k]*C(k,j) ----
__global__ void k_coef(const float* __restrict__ gL, const float* __restrict__ gH, int K,
                       float* __restrict__ cL, float* __restrict__ cH) {
    if (threadIdx.x == 0 && blockIdx.x == 0) {
        for (int j = 0; j <= K; ++j) {
            double s = 0.0;
            double C = 1.0;
            for (int k = j; k <= K; ++k) {
                s += (double)gH[k] * C;
                C = C * (double)(k + 1) / (double)(k + 1 - j);
            }
            cH[j] = (j & 1) ? (float)(-s) : (float)s;
            cL[j] = gL[j];
        }
    }
}

// ---- single-block exclusive scan deg -> row_ptr ----
__global__ __launch_bounds__(1024) void k_scan(const int* __restrict__ deg, int N,
                                               int* __restrict__ row_ptr) {
    __shared__ int ls[1024];
    int tid = threadIdx.x;
    int chunk = (N + 1023) / 1024;
    int start = tid * chunk;
    int end = min(start + chunk, N);
    int s = 0;
    for (int i = start; i < end; ++i) s += deg[i];
    ls[tid] = s;
    __syncthreads();
    for (int off = 1; off < 1024; off <<= 1) {
        int v = (tid >= off) ? ls[tid - off] : 0;
        __syncthreads();
        ls[tid] += v;
        __syncthreads();
    }
    int run = ls[tid] - s;
    for (int i = start; i < end; ++i) {
        row_ptr[i] = run;
        run += deg[i];
    }
    if (tid == 1023) row_ptr[N] = run;
}

// ---- scatter edges into CSR (by dst) ----
__global__ void k_scatter(const int* __restrict__ src, const int* __restrict__ dst, int E,
                          const int* __restrict__ row_ptr, int* __restrict__ fill,
                          const float* __restrict__ dinv, int* __restrict__ csr_src,
                          float* __restrict__ csr_w) {
    int i = blockIdx.x * blockDim.x + threadIdx.x;
    if (i < E) {
        int s = src[i], d = dst[i];
        int pos = row_ptr[d] + atomicAdd(&fill[d], 1);
        csr_src[pos] = s;
        csr_w[pos] = dinv[s] * dinv[d];
    }
}

// ---- input GEMM: H = X @ W + b (+ optional acc init) ----
// BM=64, BN=128, BK=20, 256 threads, 8x4 frag, transposed As, double-buffered LDS.
__global__ __launch_bounds__(256) void k_gemm_in(
    const float* __restrict__ X, const float* __restrict__ W, const float* __restrict__ b,
    float* __restrict__ H, float* __restrict__ accL, float* __restrict__ accH,
    const float* __restrict__ cL, const float* __restrict__ cH, int M, int Kdim,
    int init_acc) {
    const int BK = 20;
    __shared__ float As[2][BK][68];
    __shared__ float Bs[2][BK][128];
    int tid = threadIdx.x;
    int tx = tid & 31, ty = tid >> 5;  // ty 0..7
    int row0 = blockIdx.x * 64;
    int m = tid >> 2, qq = tid & 3;  // staging: column m, float4 group qq
    int r = row0 + m;
    float acc[8][4] = {};
    int nc = Kdim / BK;  // 25 for Kdim=500

    float4 xv, xw, b0, b1, b2;
    auto loadX = [&](int k0, float4& v, float4& w4) {
        v = make_float4(0.f, 0.f, 0.f, 0.f);
        w4 = make_float4(0.f, 0.f, 0.f, 0.f);
        if (r < M) {
            v = *(const float4*)&X[(long)r * Kdim + k0 + qq * 4];
            if (qq == 0) w4 = *(const float4*)&X[(long)r * Kdim + k0 + 16];
        }
    };
    auto storeX = [&](int buf, float4 v, float4 w4) {
        int kk = qq * 4;
        As[buf][kk + 0][m] = v.x;
        As[buf][kk + 1][m] = v.y;
        As[buf][kk + 2][m] = v.z;
        As[buf][kk + 3][m] = v.w;
        if (qq == 0) {
            As[buf][16][m] = w4.x;
            As[buf][17][m] = w4.y;
            As[buf][18][m] = w4.z;
            As[buf][19][m] = w4.w;
        }
    };
    auto loadW = [&](int k0, float4& c0, float4& c1, float4& c2) {
        int l = tid;
        c0 = *(const float4*)&W[(long)(k0 + (l >> 5)) * 128 + (l & 31) * 4];
        l = tid + 256;
        c1 = *(const float4*)&W[(long)(k0 + (l >> 5)) * 128 + (l & 31) * 4];
        if (tid < 128) {
            l = tid + 512;
            c2 = *(const float4*)&W[(long)(k0 + (l >> 5)) * 128 + (l & 31) * 4];
        }
    };
    auto storeW = [&](int buf, float4 c0, float4 c1, float4 c2) {
        int l = tid;
        *(float4*)&Bs[buf][l >> 5][(l & 31) * 4] = c0;
        l = tid + 256;
        *(float4*)&Bs[buf][l >> 5][(l & 31) * 4] = c1;
        if (tid < 128) {
            l = tid + 512;
            *(float4*)&Bs[buf][l >> 5][(l & 31) * 4] = c2;
        }
    };

    loadX(0, xv, xw);
    loadW(0, b0, b1, b2);
    storeX(0, xv, xw);
    storeW(0, b0, b1, b2);
    __syncthreads();
    for (int c = 0; c < nc; ++c) {
        int cur = c & 1;
        if (c + 1 < nc) {
            loadX((c + 1) * BK, xv, xw);
            loadW((c + 1) * BK, b0, b1, b2);
        }
#pragma unroll
        for (int k = 0; k < BK; ++k) {
            float4 a0 = *(const float4*)&As[cur][k][ty * 8];
            float4 a1 = *(const float4*)&As[cur][k][ty * 8 + 4];
            float4 bb = *(const float4*)&Bs[cur][k][tx * 4];
            float a[8] = {a0.x, a0.y, a0.z, a0.w, a1.x, a1.y, a1.z, a1.w};
#pragma unroll
            for (int i = 0; i < 8; ++i) {
                acc[i][0] += a[i] * bb.x;
                acc[i][1] += a[i] * bb.y;
                acc[i][2] += a[i] * bb.z;
                acc[i][3] += a[i] * bb.w;
            }
        }
        if (c + 1 < nc) {
            storeX(1 - cur, xv, xw);
            storeW(1 - cur, b0, b1, b2);
        }
        __syncthreads();
    }
    float g0 = cL[0], h0 = cH[0];
    float4 bias = *(const float4*)&b[tx * 4];
    float bv[4] = {bias.x, bias.y, bias.z, bias.w};
#pragma unroll
    for (int i = 0; i < 8; ++i) {
        int rr = row0 + ty * 8 + i;
        if (rr < M) {
            long idx = (long)rr * 128 + tx * 4;
            float4 vh, vl, vvh;
            float* ph = (float*)&vh;
            float* pl = (float*)&vl;
            float* pH = (float*)&vvh;
#pragma unroll
            for (int j = 0; j < 4; ++j) {
                float v = acc[i][j] + bv[j];
                ph[j] = v;
                pl[j] = g0 * v;
                pH[j] = h0 * v;
            }
            *(float4*)&H[idx] = vh;
            if (init_acc) {
                *(float4*)&accL[idx] = vl;
                *(float4*)&accH[idx] = vvh;
            }
        }
    }
}

// ---- prop step: t_out = P t_in (+ optional acc RMW for fallback path) ----
// one wave per node; half-wave per edge-parity; full 512B row per half-wave; unroll 4
__global__ __launch_bounds__(256) void k_prop(
    const int* __restrict__ row_ptr, const int* __restrict__ csr_src,
    const float* __restrict__ csr_w, const float* __restrict__ t_in,
    float* __restrict__ t_out, float* __restrict__ accL, float* __restrict__ accH,
    const float* __restrict__ cL, const float* __restrict__ cH, int j, int N, int write_t,
    int do_acc) {
    int wave = threadIdx.x >> 6;
    int lane = threadIdx.x & 63;
    int half = lane >> 5;
    int l5 = lane & 31;
    int node = blockIdx.x * 4 + wave;
    if (node >= N) return;
    int e0 = row_ptr[node], e1 = row_ptr[node + 1];
    float sx = 0.f, sy = 0.f, sz = 0.f, sw = 0.f;
    int e = e0 + half;
    for (; e + 6 < e1; e += 8) {
        int i0 = csr_src[e], i1 = csr_src[e + 2], i2 = csr_src[e + 4], i3 = csr_src[e + 6];
        float w0 = csr_w[e], w1 = csr_w[e + 2], w2 = csr_w[e + 4], w3 = csr_w[e + 6];
        float4 v0 = *(const float4*)&t_in[(long)i0 * HIDF + l5 * 4];
        float4 v1 = *(const float4*)&t_in[(long)i1 * HIDF + l5 * 4];
        float4 v2 = *(const float4*)&t_in[(long)i2 * HIDF + l5 * 4];
        float4 v3 = *(const float4*)&t_in[(long)i3 * HIDF + l5 * 4];
        sx += w0 * v0.x + w1 * v1.x + w2 * v2.x + w3 * v3.x;
        sy += w0 * v0.y + w1 * v1.y + w2 * v2.y + w3 * v3.y;
        sz += w0 * v0.z + w1 * v1.z + w2 * v2.z + w3 * v3.z;
        sw += w0 * v0.w + w1 * v1.w + w2 * v2.w + w3 * v3.w;
    }
    for (; e < e1; e += 2) {
        int i0 = csr_src[e];
        float w0 = csr_w[e];
        float4 v0 = *(const float4*)&t_in[(long)i0 * HIDF + l5 * 4];
        sx += w0 * v0.x;
        sy += w0 * v0.y;
        sz += w0 * v0.z;
        sw += w0 * v0.w;
    }
    sx += __shfl_xor(sx, 32);
    sy += __shfl_xor(sy, 32);
    sz += __shfl_xor(sz, 32);
    sw += __shfl_xor(sw, 32);
    if (half == 0) {
        long base = (long)node * HIDF + l5 * 4;
        if (write_t) {
            float4 o = {sx, sy, sz, sw};
            *(float4*)&t_out[base] = o;
        }
        if (do_acc) {
            float gL = cL[j], gH = cH[j];
            float4 aL = *(const float4*)&accL[base];
            float4 aH = *(const float4*)&accH[base];
            aL.x += gL * sx;
            aL.y += gL * sy;
            aL.z += gL * sz;
            aL.w += gL * sw;
            aH.x += gH * sx;
            aH.y += gH * sy;
            aH.z += gH * sz;
            aH.w += gH * sw;
            *(float4*)&accL[base] = aL;
            *(float4*)&accH[base] = aH;
        }
    }
}

// ---- fused basis combine + BN stats (deferred path) ----
// accL = sum_j cL[j] t_j ; accH = sum_j cH[j] t_j ; stats of both into sums[512]
__global__ __launch_bounds__(256) void k_combine(
    const float* __restrict__ tb, long tstride, int K, float* __restrict__ accL,
    float* __restrict__ accH, const float* __restrict__ cL, const float* __restrict__ cH,
    int N, float* __restrict__ sums) {
    int tid = threadIdx.x;
    int l5 = tid & 31;
    int g = tid >> 5;
    float4 s1 = {0, 0, 0, 0}, s2 = {0, 0, 0, 0}, s3 = {0, 0, 0, 0}, s4 = {0, 0, 0, 0};
    for (long r = blockIdx.x * 8 + g; r < N; r += (long)gridDim.x * 8) {
        const float* p = tb + r * HIDF + l5 * 4;
        float4 aL = {0, 0, 0, 0}, aH = {0, 0, 0, 0};
        for (int j = 0; j <= K; ++j) {
            float4 v = *(const float4*)(p + (long)j * tstride);
            float gL = cL[j], gH = cH[j];
            aL.x += gL * v.x; aL.y += gL * v.y; aL.z += gL * v.z; aL.w += gL * v.w;
            aH.x += gH * v.x; aH.y += gH * v.y; aH.z += gH * v.z; aH.w += gH * v.w;
        }
        long base = r * HIDF + l5 * 4;
        *(float4*)&accL[base] = aL;
        *(float4*)&accH[base] = aH;
        s1.x += aL.x; s1.y += aL.y; s1.z += aL.z; s1.w += aL.w;
        s2.x += aL.x * aL.x; s2.y += aL.y * aL.y; s2.z += aL.z * aL.z; s2.w += aL.w * aL.w;
        s3.x += aH.x; s3.y += aH.y; s3.z += aH.z; s3.w += aH.w;
        s4.x += aH.x * aH.x; s4.y += aH.y * aH.y; s4.z += aH.z * aH.z; s4.w += aH.w * aH.w;
    }
    __shared__ float4 ls1[256], ls2[256], ls3[256], ls4[256];
    ls1[tid] = s1;
    ls2[tid] = s2;
    ls3[tid] = s3;
    ls4[tid] = s4;
    __syncthreads();
    if (tid < 32) {
        float4 a = ls1[tid], bq = ls2[tid], c = ls3[tid], d = ls4[tid];
        for (int gg = 1; gg < 8; ++gg) {
            float4 t;
            t = ls1[gg * 32 + tid]; a.x += t.x; a.y += t.y; a.z += t.z; a.w += t.w;
            t = ls2[gg * 32 + tid]; bq.x += t.x; bq.y += t.y; bq.z += t.z; bq.w += t.w;
            t = ls3[gg * 32 + tid]; c.x += t.x; c.y += t.y; c.z += t.z; c.w += t.w;
            t = ls4[gg * 32 + tid]; d.x += t.x; d.y += t.y; d.z += t.z; d.w += t.w;
        }
        int f = tid * 4;
        atomicAdd(&sums[f + 0], a.x); atomicAdd(&sums[f + 1], a.y);
        atomicAdd(&sums[f + 2], a.z); atomicAdd(&sums[f + 3], a.w);
        atomicAdd(&sums[128 + f + 0], bq.x); atomicAdd(&sums[128 + f + 1], bq.y);
        atomicAdd(&sums[128 + f + 2], bq.z); atomicAdd(&sums[128 + f + 3], bq.w);
        atomicAdd(&sums[256 + f + 0], c.x); atomicAdd(&sums[256 + f + 1], c.y);
        atomicAdd(&sums[256 + f + 2], c.z); atomicAdd(&sums[256 + f + 3], c.w);
        atomicAdd(&sums[384 + f + 0], d.x); atomicAdd(&sums[384 + f + 1], d.y);
        atomicAdd(&sums[384 + f + 2], d.z); atomicAdd(&sums[384 + f + 3], d.w);
    }
}

// ---- standalone BN stats (fallback path) ----
__global__ __launch_bounds__(256) void k_stats(const float* __restrict__ accL,
                                               const float* __restrict__ accH, int N,
                                               float* __restrict__ sums) {
    int tid = threadIdx.x;
    int l5 = tid & 31;
    int g = tid >> 5;
    float4 l1 = {0, 0, 0, 0}, l2 = {0, 0, 0, 0}, h1 = {0, 0, 0, 0}, h2 = {0, 0, 0, 0};
    for (int r = blockIdx.x * 8 + g; r < N; r += gridDim.x * 8) {
        float4 v = *(const float4*)&accL[(long)r * HIDF + l5 * 4];
        l1.x += v.x; l1.y += v.y; l1.z += v.z; l1.w += v.w;
        l2.x += v.x * v.x; l2.y += v.y * v.y; l2.z += v.z * v.z; l2.w += v.w * v.w;
        float4 u = *(const float4*)&accH[(long)r * HIDF + l5 * 4];
        h1.x += u.x; h1.y += u.y; h1.z += u.z; h1.w += u.w;
        h2.x += u.x * u.x; h2.y += u.y * u.y; h2.z += u.z * u.z; h2.w += u.w * u.w;
    }
    __shared__ float4 s1[256], s2[256], s3[256], s4[256];
    s1[tid] = l1;
    s2[tid] = l2;
    s3[tid] = h1;
    s4[tid] = h2;
    __syncthreads();
    if (tid < 32) {
        float4 a = s1[tid], bq = s2[tid], c = s3[tid], d = s4[tid];
        for (int gg = 1; gg < 8; ++gg) {
            float4 t;
            t = s1[gg * 32 + tid]; a.x += t.x; a.y += t.y; a.z += t.z; a.w += t.w;
            t = s2[gg * 32 + tid]; bq.x += t.x; bq.y += t.y; bq.z += t.z; bq.w += t.w;
            t = s3[gg * 32 + tid]; c.x += t.x; c.y += t.y; c.z += t.z; c.w += t.w;
            t = s4[gg * 32 + tid]; d.x += t.x; d.y += t.y; d.z += t.z; d.w += t.w;
        }
        int f = tid * 4;
        atomicAdd(&sums[f + 0], a.x); atomicAdd(&sums[f + 1], a.y);
        atomicAdd(&sums[f + 2], a.z); atomicAdd(&sums[f + 3], a.w);
        atomicAdd(&sums[128 + f + 0], bq.x); atomicAdd(&sums[128 + f + 1], bq.y);
        atomicAdd(&sums[128 + f + 2], bq.z); atomicAdd(&sums[128 + f + 3], bq.w);
        atomicAdd(&sums[256 + f + 0], c.x); atomicAdd(&sums[256 + f + 1], c.y);
        atomicAdd(&sums[256 + f + 2], c.z); atomicAdd(&sums[256 + f + 3], c.w);
        atomicAdd(&sums[384 + f + 0], d.x); atomicAdd(&sums[384 + f + 1], d.y);
        atomicAdd(&sums[384 + f + 2], d.z); atomicAdd(&sums[384 + f + 3], d.w);
    }
}

// ---- finalize BN affine for both encoders ----
__global__ void k_bnfin(const float* __restrict__ sums, int N, const float* __restrict__ scale,
                        const float* __restrict__ shift, float* __restrict__ a_mul,
                        float* __restrict__ a_add) {
    int f = threadIdx.x;
    for (int enc = 0; enc < 2; ++enc) {
        float mu = sums[enc * 256 + f] / (float)N;
        float var = sums[enc * 256 + 128 + f] / (float)N - mu * mu;
        float rstd = rsqrtf(var + 1e-5f);
        float am = rstd * scale[f];
        a_mul[enc * 128 + f] = am;
        a_add[enc * 128 + f] = shift[f] - mu * am;
    }
}

// ---- up GEMM, BN fused at staging, bias+relu; grid.y = encoder ----
__global__ __launch_bounds__(512) void k_gemm_up(
    const float* __restrict__ accL, const float* __restrict__ accH,
    const float* __restrict__ W, const float* __restrict__ bias,
    const float* __restrict__ a_mul, const float* __restrict__ a_add,
    float* __restrict__ out, int M) {
    int enc = blockIdx.y;
    const float* A = enc ? accH : accL;
    float* O = out + (size_t)enc * M * 128;
    __shared__ float As[16][132];
    __shared__ float Bs[16][128];
    __shared__ float ams[128], aas[128];
    int tid = threadIdx.x;
    int tx = tid & 31, ty = tid >> 5;
    int row0 = blockIdx.x * 128;
    if (tid < 128) {
        ams[tid] = a_mul[enc * 128 + tid];
        aas[tid] = a_add[enc * 128 + tid];
    }
    __syncthreads();
    float acc[8][4] = {};
    for (int k0 = 0; k0 < 128; k0 += 16) {
        {
            int m = tid >> 2, q = tid & 3;
            int r = row0 + m;
            float4 v = {0.f, 0.f, 0.f, 0.f};
            if (r < M) v = *(const float4*)&A[(long)r * 128 + k0 + q * 4];
            int kk = q * 4;
            As[kk + 0][m] = v.x * ams[k0 + kk + 0] + aas[k0 + kk + 0];
            As[kk + 1][m] = v.y * ams[k0 + kk + 1] + aas[k0 + kk + 1];
            As[kk + 2][m] = v.z * ams[k0 + kk + 2] + aas[k0 + kk + 2];
            As[kk + 3][m] = v.w * ams[k0 + kk + 3] + aas[k0 + kk + 3];
        }
        {
            int k = tid >> 5, n = (tid & 31) * 4;
            *(float4*)&Bs[k][n] = *(const float4*)&W[(long)(k0 + k) * 128 + n];
        }
        __syncthreads();
#pragma unroll
        for (int k = 0; k < 16; ++k) {
            float4 a0 = *(const float4*)&As[k][ty * 8];
            float4 a1 = *(const float4*)&As[k][ty * 8 + 4];
            float4 bb = *(const float4*)&Bs[k][tx * 4];
            float a[8] = {a0.x, a0.y, a0.z, a0.w, a1.x, a1.y, a1.z, a1.w};
#pragma unroll
            for (int i = 0; i < 8; ++i) {
                acc[i][0] += a[i] * bb.x;
                acc[i][1] += a[i] * bb.y;
                acc[i][2] += a[i] * bb.z;
                acc[i][3] += a[i] * bb.w;
            }
        }
        __syncthreads();
    }
    float4 bv = *(const float4*)&bias[tx * 4];
    float bb[4] = {bv.x, bv.y, bv.z, bv.w};
#pragma unroll
    for (int i = 0; i < 8; ++i) {
        int r = row0 + ty * 8 + i;
        if (r < M) {
            float4 o;
            o.x = fmaxf(acc[i][0] + bb[0], 0.0f);
            o.y = fmaxf(acc[i][1] + bb[1], 0.0f);
            o.z = fmaxf(acc[i][2] + bb[2], 0.0f);
            o.w = fmaxf(acc[i][3] + bb[3], 0.0f);
            *(float4*)&O[(long)r * 128 + tx * 4] = o;
        }
    }
}

extern "C" void kernel_launch(void* const* d_in, const int* in_sizes, int n_in, void* d_out,
                              int out_size, void* d_ws, size_t ws_size, hipStream_t stream) {
    const float* x = (const float*)d_in[0];
    const int* edge_index = (const int*)d_in[1];
    const float* W_in = (const float*)d_in[2];
    const float* b_in = (const float*)d_in[3];
    const float* gamma_L = (const float*)d_in[4];
    const float* gamma_H = (const float*)d_in[5];
    const float* bn_scale = (const float*)d_in[6];
    const float* bn_shift = (const float*)d_in[7];
    const float* W_up = (const float*)d_in[8];
    const float* b_up = (const float*)d_in[9];
    float* out = (float*)d_out;

    const int HID = in_sizes[3];       // 128
    const int IN = in_sizes[2] / HID;  // 500
    const int N = in_sizes[0] / IN;    // 50000
    const int E = in_sizes[1] / 2;     // 800000
    const int K = in_sizes[4] - 1;     // 10

    const int* src = edge_index;
    const int* dst = edge_index + E;

    char* base = (char*)d_ws;
    size_t off = 0;
    auto take = [&](size_t bytes) -> char* {
        char* r = base + off;
        off += alup(bytes);
        return r;
    };
    int* deg = (int*)take((size_t)N * 4);
    int* row_ptr = (int*)take((size_t)(N + 1) * 4);
    int* fill = (int*)take((size_t)N * 4);
    float* dinv = (float*)take((size_t)N * 4);
    int* csr_src = (int*)take((size_t)E * 4);
    float* csr_w = (float*)take((size_t)E * 4);
    float* accL = (float*)take((size_t)N * HID * 4);
    float* accH = (float*)take((size_t)N * HID * 4);
    float* sums = (float*)take(512 * 4);
    float* cL = (float*)take(64 * 4);
    float* cH = (float*)take(64 * 4);
    float* a_mul = (float*)take(256 * 4);
    float* a_add = (float*)take(256 * 4);
    size_t per = alup((size_t)N * HID * 4);
    long stride_elems = (long)(per / 4);
    float* tb = (float*)(base + off);
    // deferred path needs K+1 basis buffers; fallback needs 2 (ping-pong)
    bool deferred = (off + (size_t)(K + 1) * per) <= ws_size && K < 60;

    hipMemsetAsync(deg, 0, (size_t)N * 4, stream);
    hipMemsetAsync(fill, 0, (size_t)N * 4, stream);
    hipMemsetAsync(sums, 0, 512 * 4, stream);

    k_coef<<<1, 64, 0, stream>>>(gamma_L, gamma_H, K, cL, cH);
    k_deg<<<cdiv(E, 256), 256, 0, stream>>>(dst, E, deg);
    k_dinv<<<cdiv(N, 256), 256, 0, stream>>>(deg, N, dinv);
    k_scan<<<1, 1024, 0, stream>>>(deg, N, row_ptr);
    k_scatter<<<cdiv(E, 256), 256, 0, stream>>>(src, dst, E, row_ptr, fill, dinv, csr_src,
                                                csr_w);

    if (deferred) {
        // t_0 = h lands in tb[0]; no acc init
        k_gemm_in<<<cdiv(N, 64), 256, 0, stream>>>(x, W_in, b_in, tb, accL, accH, cL, cH, N,
                                                   IN, 0);
        for (int j = 1; j <= K; ++j) {
            const float* tin = tb + (long)(j - 1) * stride_elems;
            float* tout = tb + (long)j * stride_elems;
            k_prop<<<cdiv(N, 4), 256, 0, stream>>>(row_ptr, csr_src, csr_w, tin, tout, accL,
                                                   accH, cL, cH, j, N, 1, 0);
        }
        k_combine<<<512, 256, 0, stream>>>(tb, stride_elems, K, accL, accH, cL, cH, N, sums);
    } else {
        float* h = tb;
        float* ta = tb + stride_elems;
        k_gemm_in<<<cdiv(N, 64), 256, 0, stream>>>(x, W_in, b_in, h, accL, accH, cL, cH, N,
                                                   IN, 1);
        const float* tin = h;
        float* tout = ta;
        for (int j = 1; j <= K; ++j) {
            int write_t = (j < K) ? 1 : 0;
            k_prop<<<cdiv(N, 4), 256, 0, stream>>>(row_ptr, csr_src, csr_w, tin, tout, accL,
                                                   accH, cL, cH, j, N, write_t, 1);
            const float* nt = tout;
            tout = (nt == ta) ? h : ta;
            tin = nt;
        }
        k_stats<<<200, 256, 0, stream>>>(accL, accH, N, sums);
    }

    k_bnfin<<<1, 128, 0, stream>>>(sums, N, bn_scale, bn_shift, a_mul, a_add);
    dim3 gup(cdiv(N, 128), 2);
    k_gemm_up<<<gup, 512, 0, stream>>>(accL, accH, W_up, b_up, a_mul, a_add, out, N);
}

// Round 5
// 1142.201 us; speedup vs baseline: 1.0487x; 1.0487x over previous
//
#include <hip/hip_runtime.h>

#define HIDF 128

static inline int cdiv(int a, int b) { return (a + b - 1) / b; }
static inline size_t alup(size_t b) { return (b + 255) & ~(size_t)255; }

// ---- degree count over dst ----
__global__ void k_deg(const int* __restrict__ dst, int E, int* __restrict__ deg) {
    int i = blockIdx.x * blockDim.x + threadIdx.x;
    if (i < E) atomicAdd(&deg[dst[i]], 1);
}

// ---- dinv = rsqrt(max(deg,1)) ----
__global__ void k_dinv(const int* __restrict__ deg, int N, float* __restrict__ dinv) {
    int i = blockIdx.x * blockDim.x + threadIdx.x;
    if (i < N) {
        float d = (float)deg[i];
        dinv[i] = rsqrtf(fmaxf(d, 1.0f));
    }
}

// ---- coefficients: cL[j]=gamma_L[j]; cH[j]=(-1)^j sum_{k>=j} gamma_H[k]*C(k,j) ----
__global__ void k_coef(const float* __restrict__ gL, const float* __restrict__ gH, int K,
                       float* __restrict__ cL, float* __restrict__ cH) {
    if (threadIdx.x == 0 && blockIdx.x == 0) {
        for (int j = 0; j <= K; ++j) {
            double s = 0.0;
            double C = 1.0;
            for (int k = j; k <= K; ++k) {
                s += (double)gH[k] * C;
                C = C * (double)(k + 1) / (double)(k + 1 - j);
            }
            cH[j] = (j & 1) ? (float)(-s) : (float)s;
            cL[j] = gL[j];
        }
    }
}

// ---- single-block exclusive scan deg -> row_ptr ----
__global__ __launch_bounds__(1024) void k_scan(const int* __restrict__ deg, int N,
                                               int* __restrict__ row_ptr) {
    __shared__ int ls[1024];
    int tid = threadIdx.x;
    int chunk = (N + 1023) / 1024;
    int start = tid * chunk;
    int end = min(start + chunk, N);
    int s = 0;
    for (int i = start; i < end; ++i) s += deg[i];
    ls[tid] = s;
    __syncthreads();
    for (int off = 1; off < 1024; off <<= 1) {
        int v = (tid >= off) ? ls[tid - off] : 0;
        __syncthreads();
        ls[tid] += v;
        __syncthreads();
    }
    int run = ls[tid] - s;
    for (int i = start; i < end; ++i) {
        row_ptr[i] = run;
        run += deg[i];
    }
    if (tid == 1023) row_ptr[N] = run;
}

// ---- scatter edges into CSR (by dst) ----
__global__ void k_scatter(const int* __restrict__ src, const int* __restrict__ dst, int E,
                          const int* __restrict__ row_ptr, int* __restrict__ fill,
                          const float* __restrict__ dinv, int* __restrict__ csr_src,
                          float* __restrict__ csr_w) {
    int i = blockIdx.x * blockDim.x + threadIdx.x;
    if (i < E) {
        int s = src[i], d = dst[i];
        int pos = row_ptr[d] + atomicAdd(&fill[d], 1);
        csr_src[pos] = s;
        csr_w[pos] = dinv[s] * dinv[d];
    }
}

// ---- input GEMM: H = X @ W + b (+ optional acc init) ----
// Round-3 structure: BM=128, BN=128, BK=20, 512 threads, 8x4 frag, transposed As.
// Single-buffered (measured best: VGPR 40, occ 31%). Do NOT double-buffer (R4: 160 VGPR, 8% occ).
__global__ __launch_bounds__(512) void k_gemm_in(
    const float* __restrict__ X, const float* __restrict__ W, const float* __restrict__ b,
    float* __restrict__ H, float* __restrict__ accL, float* __restrict__ accH,
    const float* __restrict__ cL, const float* __restrict__ cH, int M, int Kdim,
    int init_acc) {
    const int BK = 20;
    __shared__ float As[BK][132];
    __shared__ float Bs[BK][128];
    int tid = threadIdx.x;
    int tx = tid & 31, ty = tid >> 5;  // ty 0..15
    int row0 = blockIdx.x * 128;
    float acc[8][4] = {};
    for (int k0 = 0; k0 < Kdim; k0 += BK) {
        // stage X: 128 rows x 5 float4 = 640 float4 loads
        for (int l = tid; l < 640; l += 512) {
            int m = l / 5, q = l % 5;
            int r = row0 + m;
            float4 v = {0.f, 0.f, 0.f, 0.f};
            if (r < M) v = *(const float4*)&X[(long)r * Kdim + k0 + q * 4];
            As[q * 4 + 0][m] = v.x;
            As[q * 4 + 1][m] = v.y;
            As[q * 4 + 2][m] = v.z;
            As[q * 4 + 3][m] = v.w;
        }
        // stage W: 20x128 = 640 float4
        for (int l = tid; l < 640; l += 512) {
            int k = l >> 5, n = (l & 31) * 4;
            *(float4*)&Bs[k][n] = *(const float4*)&W[(long)(k0 + k) * 128 + n];
        }
        __syncthreads();
#pragma unroll
        for (int k = 0; k < BK; ++k) {
            float4 a0 = *(const float4*)&As[k][ty * 8];
            float4 a1 = *(const float4*)&As[k][ty * 8 + 4];
            float4 bb = *(const float4*)&Bs[k][tx * 4];
            float a[8] = {a0.x, a0.y, a0.z, a0.w, a1.x, a1.y, a1.z, a1.w};
#pragma unroll
            for (int i = 0; i < 8; ++i) {
                acc[i][0] += a[i] * bb.x;
                acc[i][1] += a[i] * bb.y;
                acc[i][2] += a[i] * bb.z;
                acc[i][3] += a[i] * bb.w;
            }
        }
        __syncthreads();
    }
    float g0 = cL[0], h0 = cH[0];
    float4 bias = *(const float4*)&b[tx * 4];
    float bv[4] = {bias.x, bias.y, bias.z, bias.w};
#pragma unroll
    for (int i = 0; i < 8; ++i) {
        int r = row0 + ty * 8 + i;
        if (r < M) {
            long idx = (long)r * 128 + tx * 4;
            float4 vh, vl, vvh;
            float* ph = (float*)&vh;
            float* pl = (float*)&vl;
            float* pH = (float*)&vvh;
#pragma unroll
            for (int j = 0; j < 4; ++j) {
                float v = acc[i][j] + bv[j];
                ph[j] = v;
                pl[j] = g0 * v;
                pH[j] = h0 * v;
            }
            *(float4*)&H[idx] = vh;
            if (init_acc) {
                *(float4*)&accL[idx] = vl;
                *(float4*)&accH[idx] = vvh;
            }
        }
    }
}

// ---- prop step: t_out = P t_in (+ optional acc RMW for fallback path) ----
// one wave per node; half-wave per edge-parity; full 512B row per half-wave; unroll 8
__global__ __launch_bounds__(256) void k_prop(
    const int* __restrict__ row_ptr, const int* __restrict__ csr_src,
    const float* __restrict__ csr_w, const float* __restrict__ t_in,
    float* __restrict__ t_out, float* __restrict__ accL, float* __restrict__ accH,
    const float* __restrict__ cL, const float* __restrict__ cH, int j, int N, int write_t,
    int do_acc) {
    int wave = threadIdx.x >> 6;
    int lane = threadIdx.x & 63;
    int half = lane >> 5;
    int l5 = lane & 31;
    int node = blockIdx.x * 4 + wave;
    if (node >= N) return;
    int e0 = row_ptr[node], e1 = row_ptr[node + 1];
    float sx = 0.f, sy = 0.f, sz = 0.f, sw = 0.f;
    int e = e0 + half;
    // unroll 8 per half (stride 16): 8 independent row-gathers in flight per half-wave
    for (; e + 14 < e1; e += 16) {
        int i0 = csr_src[e],      i1 = csr_src[e + 2],  i2 = csr_src[e + 4],  i3 = csr_src[e + 6];
        int i4 = csr_src[e + 8],  i5 = csr_src[e + 10], i6 = csr_src[e + 12], i7 = csr_src[e + 14];
        float w0 = csr_w[e],      w1 = csr_w[e + 2],  w2 = csr_w[e + 4],  w3 = csr_w[e + 6];
        float w4 = csr_w[e + 8],  w5 = csr_w[e + 10], w6 = csr_w[e + 12], w7 = csr_w[e + 14];
        float4 v0 = *(const float4*)&t_in[(long)i0 * HIDF + l5 * 4];
        float4 v1 = *(const float4*)&t_in[(long)i1 * HIDF + l5 * 4];
        float4 v2 = *(const float4*)&t_in[(long)i2 * HIDF + l5 * 4];
        float4 v3 = *(const float4*)&t_in[(long)i3 * HIDF + l5 * 4];
        float4 v4 = *(const float4*)&t_in[(long)i4 * HIDF + l5 * 4];
        float4 v5 = *(const float4*)&t_in[(long)i5 * HIDF + l5 * 4];
        float4 v6 = *(const float4*)&t_in[(long)i6 * HIDF + l5 * 4];
        float4 v7 = *(const float4*)&t_in[(long)i7 * HIDF + l5 * 4];
        sx += w0 * v0.x + w1 * v1.x + w2 * v2.x + w3 * v3.x;
        sy += w0 * v0.y + w1 * v1.y + w2 * v2.y + w3 * v3.y;
        sz += w0 * v0.z + w1 * v1.z + w2 * v2.z + w3 * v3.z;
        sw += w0 * v0.w + w1 * v1.w + w2 * v2.w + w3 * v3.w;
        sx += w4 * v4.x + w5 * v5.x + w6 * v6.x + w7 * v7.x;
        sy += w4 * v4.y + w5 * v5.y + w6 * v6.y + w7 * v7.y;
        sz += w4 * v4.z + w5 * v5.z + w6 * v6.z + w7 * v7.z;
        sw += w4 * v4.w + w5 * v5.w + w6 * v6.w + w7 * v7.w;
    }
    for (; e + 6 < e1; e += 8) {
        int i0 = csr_src[e], i1 = csr_src[e + 2], i2 = csr_src[e + 4], i3 = csr_src[e + 6];
        float w0 = csr_w[e], w1 = csr_w[e + 2], w2 = csr_w[e + 4], w3 = csr_w[e + 6];
        float4 v0 = *(const float4*)&t_in[(long)i0 * HIDF + l5 * 4];
        float4 v1 = *(const float4*)&t_in[(long)i1 * HIDF + l5 * 4];
        float4 v2 = *(const float4*)&t_in[(long)i2 * HIDF + l5 * 4];
        float4 v3 = *(const float4*)&t_in[(long)i3 * HIDF + l5 * 4];
        sx += w0 * v0.x + w1 * v1.x + w2 * v2.x + w3 * v3.x;
        sy += w0 * v0.y + w1 * v1.y + w2 * v2.y + w3 * v3.y;
        sz += w0 * v0.z + w1 * v1.z + w2 * v2.z + w3 * v3.z;
        sw += w0 * v0.w + w1 * v1.w + w2 * v2.w + w3 * v3.w;
    }
    for (; e < e1; e += 2) {
        int i0 = csr_src[e];
        float w0 = csr_w[e];
        float4 v0 = *(const float4*)&t_in[(long)i0 * HIDF + l5 * 4];
        sx += w0 * v0.x;
        sy += w0 * v0.y;
        sz += w0 * v0.z;
        sw += w0 * v0.w;
    }
    sx += __shfl_xor(sx, 32);
    sy += __shfl_xor(sy, 32);
    sz += __shfl_xor(sz, 32);
    sw += __shfl_xor(sw, 32);
    if (half == 0) {
        long base = (long)node * HIDF + l5 * 4;
        if (write_t) {
            float4 o = {sx, sy, sz, sw};
            *(float4*)&t_out[base] = o;
        }
        if (do_acc) {
            float gL = cL[j], gH = cH[j];
            float4 aL = *(const float4*)&accL[base];
            float4 aH = *(const float4*)&accH[base];
            aL.x += gL * sx;
            aL.y += gL * sy;
            aL.z += gL * sz;
            aL.w += gL * sw;
            aH.x += gH * sx;
            aH.y += gH * sy;
            aH.z += gH * sz;
            aH.w += gH * sw;
            *(float4*)&accL[base] = aL;
            *(float4*)&accH[base] = aH;
        }
    }
}

// ---- fused basis combine + BN stats (deferred path) ----
__global__ __launch_bounds__(256) void k_combine(
    const float* __restrict__ tb, long tstride, int K, float* __restrict__ accL,
    float* __restrict__ accH, const float* __restrict__ cL, const float* __restrict__ cH,
    int N, float* __restrict__ sums) {
    int tid = threadIdx.x;
    int l5 = tid & 31;
    int g = tid >> 5;
    float4 s1 = {0, 0, 0, 0}, s2 = {0, 0, 0, 0}, s3 = {0, 0, 0, 0}, s4 = {0, 0, 0, 0};
    for (long r = blockIdx.x * 8 + g; r < N; r += (long)gridDim.x * 8) {
        const float* p = tb + r * HIDF + l5 * 4;
        float4 aL = {0, 0, 0, 0}, aH = {0, 0, 0, 0};
        for (int j = 0; j <= K; ++j) {
            float4 v = *(const float4*)(p + (long)j * tstride);
            float gL = cL[j], gH = cH[j];
            aL.x += gL * v.x; aL.y += gL * v.y; aL.z += gL * v.z; aL.w += gL * v.w;
            aH.x += gH * v.x; aH.y += gH * v.y; aH.z += gH * v.z; aH.w += gH * v.w;
        }
        long base = r * HIDF + l5 * 4;
        *(float4*)&accL[base] = aL;
        *(float4*)&accH[base] = aH;
        s1.x += aL.x; s1.y += aL.y; s1.z += aL.z; s1.w += aL.w;
        s2.x += aL.x * aL.x; s2.y += aL.y * aL.y; s2.z += aL.z * aL.z; s2.w += aL.w * aL.w;
        s3.x += aH.x; s3.y += aH.y; s3.z += aH.z; s3.w += aH.w;
        s4.x += aH.x * aH.x; s4.y += aH.y * aH.y; s4.z += aH.z * aH.z; s4.w += aH.w * aH.w;
    }
    __shared__ float4 ls1[256], ls2[256], ls3[256], ls4[256];
    ls1[tid] = s1;
    ls2[tid] = s2;
    ls3[tid] = s3;
    ls4[tid] = s4;
    __syncthreads();
    if (tid < 32) {
        float4 a = ls1[tid], bq = ls2[tid], c = ls3[tid], d = ls4[tid];
        for (int gg = 1; gg < 8; ++gg) {
            float4 t;
            t = ls1[gg * 32 + tid]; a.x += t.x; a.y += t.y; a.z += t.z; a.w += t.w;
            t = ls2[gg * 32 + tid]; bq.x += t.x; bq.y += t.y; bq.z += t.z; bq.w += t.w;
            t = ls3[gg * 32 + tid]; c.x += t.x; c.y += t.y; c.z += t.z; c.w += t.w;
            t = ls4[gg * 32 + tid]; d.x += t.x; d.y += t.y; d.z += t.z; d.w += t.w;
        }
        int f = tid * 4;
        atomicAdd(&sums[f + 0], a.x); atomicAdd(&sums[f + 1], a.y);
        atomicAdd(&sums[f + 2], a.z); atomicAdd(&sums[f + 3], a.w);
        atomicAdd(&sums[128 + f + 0], bq.x); atomicAdd(&sums[128 + f + 1], bq.y);
        atomicAdd(&sums[128 + f + 2], bq.z); atomicAdd(&sums[128 + f + 3], bq.w);
        atomicAdd(&sums[256 + f + 0], c.x); atomicAdd(&sums[256 + f + 1], c.y);
        atomicAdd(&sums[256 + f + 2], c.z); atomicAdd(&sums[256 + f + 3], c.w);
        atomicAdd(&sums[384 + f + 0], d.x); atomicAdd(&sums[384 + f + 1], d.y);
        atomicAdd(&sums[384 + f + 2], d.z); atomicAdd(&sums[384 + f + 3], d.w);
    }
}

// ---- standalone BN stats (fallback path) ----
__global__ __launch_bounds__(256) void k_stats(const float* __restrict__ accL,
                                               const float* __restrict__ accH, int N,
                                               float* __restrict__ sums) {
    int tid = threadIdx.x;
    int l5 = tid & 31;
    int g = tid >> 5;
    float4 l1 = {0, 0, 0, 0}, l2 = {0, 0, 0, 0}, h1 = {0, 0, 0, 0}, h2 = {0, 0, 0, 0};
    for (int r = blockIdx.x * 8 + g; r < N; r += gridDim.x * 8) {
        float4 v = *(const float4*)&accL[(long)r * HIDF + l5 * 4];
        l1.x += v.x; l1.y += v.y; l1.z += v.z; l1.w += v.w;
        l2.x += v.x * v.x; l2.y += v.y * v.y; l2.z += v.z * v.z; l2.w += v.w * v.w;
        float4 u = *(const float4*)&accH[(long)r * HIDF + l5 * 4];
        h1.x += u.x; h1.y += u.y; h1.z += u.z; h1.w += u.w;
        h2.x += u.x * u.x; h2.y += u.y * u.y; h2.z += u.z * u.z; h2.w += u.w * u.w;
    }
    __shared__ float4 s1[256], s2[256], s3[256], s4[256];
    s1[tid] = l1;
    s2[tid] = l2;
    s3[tid] = h1;
    s4[tid] = h2;
    __syncthreads();
    if (tid < 32) {
        float4 a = s1[tid], bq = s2[tid], c = s3[tid], d = s4[tid];
        for (int gg = 1; gg < 8; ++gg) {
            float4 t;
            t = s1[gg * 32 + tid]; a.x += t.x; a.y += t.y; a.z += t.z; a.w += t.w;
            t = s2[gg * 32 + tid]; bq.x += t.x; bq.y += t.y; bq.z += t.z; bq.w += t.w;
            t = s3[gg * 32 + tid]; c.x += t.x; c.y += t.y; c.z += t.z; c.w += t.w;
            t = s4[gg * 32 + tid]; d.x += t.x; d.y += t.y; d.z += t.z; d.w += t.w;
        }
        int f = tid * 4;
        atomicAdd(&sums[f + 0], a.x); atomicAdd(&sums[f + 1], a.y);
        atomicAdd(&sums[f + 2], a.z); atomicAdd(&sums[f + 3], a.w);
        atomicAdd(&sums[128 + f + 0], bq.x); atomicAdd(&sums[128 + f + 1], bq.y);
        atomicAdd(&sums[128 + f + 2], bq.z); atomicAdd(&sums[128 + f + 3], bq.w);
        atomicAdd(&sums[256 + f + 0], c.x); atomicAdd(&sums[256 + f + 1], c.y);
        atomicAdd(&sums[256 + f + 2], c.z); atomicAdd(&sums[256 + f + 3], c.w);
        atomicAdd(&sums[384 + f + 0], d.x); atomicAdd(&sums[384 + f + 1], d.y);
        atomicAdd(&sums[384 + f + 2], d.z); atomicAdd(&sums[384 + f + 3], d.w);
    }
}

// ---- finalize BN affine for both encoders ----
__global__ void k_bnfin(const float* __restrict__ sums, int N, const float* __restrict__ scale,
                        const float* __restrict__ shift, float* __restrict__ a_mul,
                        float* __restrict__ a_add) {
    int f = threadIdx.x;
    for (int enc = 0; enc < 2; ++enc) {
        float mu = sums[enc * 256 + f] / (float)N;
        float var = sums[enc * 256 + 128 + f] / (float)N - mu * mu;
        float rstd = rsqrtf(var + 1e-5f);
        float am = rstd * scale[f];
        a_mul[enc * 128 + f] = am;
        a_add[enc * 128 + f] = shift[f] - mu * am;
    }
}

// ---- up GEMM, BN fused at staging, bias+relu; grid.y = encoder ----
__global__ __launch_bounds__(512) void k_gemm_up(
    const float* __restrict__ accL, const float* __restrict__ accH,
    const float* __restrict__ W, const float* __restrict__ bias,
    const float* __restrict__ a_mul, const float* __restrict__ a_add,
    float* __restrict__ out, int M) {
    int enc = blockIdx.y;
    const float* A = enc ? accH : accL;
    float* O = out + (size_t)enc * M * 128;
    __shared__ float As[16][132];
    __shared__ float Bs[16][128];
    __shared__ float ams[128], aas[128];
    int tid = threadIdx.x;
    int tx = tid & 31, ty = tid >> 5;
    int row0 = blockIdx.x * 128;
    if (tid < 128) {
        ams[tid] = a_mul[enc * 128 + tid];
        aas[tid] = a_add[enc * 128 + tid];
    }
    __syncthreads();
    float acc[8][4] = {};
    for (int k0 = 0; k0 < 128; k0 += 16) {
        {
            int m = tid >> 2, q = tid & 3;
            int r = row0 + m;
            float4 v = {0.f, 0.f, 0.f, 0.f};
            if (r < M) v = *(const float4*)&A[(long)r * 128 + k0 + q * 4];
            int kk = q * 4;
            As[kk + 0][m] = v.x * ams[k0 + kk + 0] + aas[k0 + kk + 0];
            As[kk + 1][m] = v.y * ams[k0 + kk + 1] + aas[k0 + kk + 1];
            As[kk + 2][m] = v.z * ams[k0 + kk + 2] + aas[k0 + kk + 2];
            As[kk + 3][m] = v.w * ams[k0 + kk + 3] + aas[k0 + kk + 3];
        }
        {
            int k = tid >> 5, n = (tid & 31) * 4;
            *(float4*)&Bs[k][n] = *(const float4*)&W[(long)(k0 + k) * 128 + n];
        }
        __syncthreads();
#pragma unroll
        for (int k = 0; k < 16; ++k) {
            float4 a0 = *(const float4*)&As[k][ty * 8];
            float4 a1 = *(const float4*)&As[k][ty * 8 + 4];
            float4 bb = *(const float4*)&Bs[k][tx * 4];
            float a[8] = {a0.x, a0.y, a0.z, a0.w, a1.x, a1.y, a1.z, a1.w};
#pragma unroll
            for (int i = 0; i < 8; ++i) {
                acc[i][0] += a[i] * bb.x;
                acc[i][1] += a[i] * bb.y;
                acc[i][2] += a[i] * bb.z;
                acc[i][3] += a[i] * bb.w;
            }
        }
        __syncthreads();
    }
    float4 bv = *(const float4*)&bias[tx * 4];
    float bb[4] = {bv.x, bv.y, bv.z, bv.w};
#pragma unroll
    for (int i = 0; i < 8; ++i) {
        int r = row0 + ty * 8 + i;
        if (r < M) {
            float4 o;
            o.x = fmaxf(acc[i][0] + bb[0], 0.0f);
            o.y = fmaxf(acc[i][1] + bb[1], 0.0f);
            o.z = fmaxf(acc[i][2] + bb[2], 0.0f);
            o.w = fmaxf(acc[i][3] + bb[3], 0.0f);
            *(float4*)&O[(long)r * 128 + tx * 4] = o;
        }
    }
}

extern "C" void kernel_launch(void* const* d_in, const int* in_sizes, int n_in, void* d_out,
                              int out_size, void* d_ws, size_t ws_size, hipStream_t stream) {
    const float* x = (const float*)d_in[0];
    const int* edge_index = (const int*)d_in[1];
    const float* W_in = (const float*)d_in[2];
    const float* b_in = (const float*)d_in[3];
    const float* gamma_L = (const float*)d_in[4];
    const float* gamma_H = (const float*)d_in[5];
    const float* bn_scale = (const float*)d_in[6];
    const float* bn_shift = (const float*)d_in[7];
    const float* W_up = (const float*)d_in[8];
    const float* b_up = (const float*)d_in[9];
    float* out = (float*)d_out;

    const int HID = in_sizes[3];       // 128
    const int IN = in_sizes[2] / HID;  // 500
    const int N = in_sizes[0] / IN;    // 50000
    const int E = in_sizes[1] / 2;     // 800000
    const int K = in_sizes[4] - 1;     // 10

    const int* src = edge_index;
    const int* dst = edge_index + E;

    char* base = (char*)d_ws;
    size_t off = 0;
    auto take = [&](size_t bytes) -> char* {
        char* r = base + off;
        off += alup(bytes);
        return r;
    };
    int* deg = (int*)take((size_t)N * 4);
    int* row_ptr = (int*)take((size_t)(N + 1) * 4);
    int* fill = (int*)take((size_t)N * 4);
    float* dinv = (float*)take((size_t)N * 4);
    int* csr_src = (int*)take((size_t)E * 4);
    float* csr_w = (float*)take((size_t)E * 4);
    float* accL = (float*)take((size_t)N * HID * 4);
    float* accH = (float*)take((size_t)N * HID * 4);
    float* sums = (float*)take(512 * 4);
    float* cL = (float*)take(64 * 4);
    float* cH = (float*)take(64 * 4);
    float* a_mul = (float*)take(256 * 4);
    float* a_add = (float*)take(256 * 4);
    size_t per = alup((size_t)N * HID * 4);
    long stride_elems = (long)(per / 4);
    float* tb = (float*)(base + off);
    bool deferred = (off + (size_t)(K + 1) * per) <= ws_size && K < 60;

    hipMemsetAsync(deg, 0, (size_t)N * 4, stream);
    hipMemsetAsync(fill, 0, (size_t)N * 4, stream);
    hipMemsetAsync(sums, 0, 512 * 4, stream);

    k_coef<<<1, 64, 0, stream>>>(gamma_L, gamma_H, K, cL, cH);
    k_deg<<<cdiv(E, 256), 256, 0, stream>>>(dst, E, deg);
    k_dinv<<<cdiv(N, 256), 256, 0, stream>>>(deg, N, dinv);
    k_scan<<<1, 1024, 0, stream>>>(deg, N, row_ptr);
    k_scatter<<<cdiv(E, 256), 256, 0, stream>>>(src, dst, E, row_ptr, fill, dinv, csr_src,
                                                csr_w);

    if (deferred) {
        k_gemm_in<<<cdiv(N, 128), 512, 0, stream>>>(x, W_in, b_in, tb, accL, accH, cL, cH, N,
                                                    IN, 0);
        for (int j = 1; j <= K; ++j) {
            const float* tin = tb + (long)(j - 1) * stride_elems;
            float* tout = tb + (long)j * stride_elems;
            k_prop<<<cdiv(N, 4), 256, 0, stream>>>(row_ptr, csr_src, csr_w, tin, tout, accL,
                                                   accH, cL, cH, j, N, 1, 0);
        }
        k_combine<<<512, 256, 0, stream>>>(tb, stride_elems, K, accL, accH, cL, cH, N, sums);
    } else {
        float* h = tb;
        float* ta = tb + stride_elems;
        k_gemm_in<<<cdiv(N, 128), 512, 0, stream>>>(x, W_in, b_in, h, accL, accH, cL, cH, N,
                                                    IN, 1);
        const float* tin = h;
        float* tout = ta;
        for (int j = 1; j <= K; ++j) {
            int write_t = (j < K) ? 1 : 0;
            k_prop<<<cdiv(N, 4), 256, 0, stream>>>(row_ptr, csr_src, csr_w, tin, tout, accL,
                                                   accH, cL, cH, j, N, write_t, 1);
            const float* nt = tout;
            tout = (nt == ta) ? h : ta;
            tin = nt;
        }
        k_stats<<<200, 256, 0, stream>>>(accL, accH, N, sums);
    }

    k_bnfin<<<1, 128, 0, stream>>>(sums, N, bn_scale, bn_shift, a_mul, a_add);
    dim3 gup(cdiv(N, 128), 2);
    k_gemm_up<<<gup, 512, 0, stream>>>(accL, accH, W_up, b_up, a_mul, a_add, out, N);
}